// Round 1
// baseline (366.733 us; speedup 1.0000x reference)
//
#include <hip/hip_runtime.h>

#define HH 224
#define WW 224
#define NS 381      // splats per image
#define BB 16       // batch
#define NPIX (BB * HH * WW)   // 802816, divisible by 256 -> 3136 blocks

// Pack per-splat constants: {px, py, -inv_two_var*log2e, cr, cg, cb, 0, 0}
__global__ __launch_bounds__(256) void splat_prep(const float* __restrict__ pos,
                                                  const float* __restrict__ col,
                                                  const float* __restrict__ siz,
                                                  float* __restrict__ ws) {
    int i = blockIdx.x * 256 + threadIdx.x;
    if (i >= BB * NS) return;
    float px = pos[2 * i + 0];
    float py = pos[2 * i + 1];
    float cr = col[3 * i + 0];
    float cg = col[3 * i + 1];
    float cb = col[3 * i + 2];
    float s  = siz[i] * (2.0f / (float)HH);
    float itv = 1.0f / (2.0f * s * s + 1e-8f);
    float negc = -itv * 1.44269504088896340736f;  // fold ln->log2 for exp2
    float4* o = (float4*)(ws + (size_t)i * 8);
    o[0] = make_float4(px, py, negc, cr);
    o[1] = make_float4(cg, cb, 0.0f, 0.0f);
}

__global__ __launch_bounds__(256) void splat_render(const float* __restrict__ ws,
                                                    float* __restrict__ out) {
    int p = blockIdx.x * 256 + threadIdx.x;
    int b   = p / (HH * WW);
    int rem = p - b * (HH * WW);
    int h = rem / WW;
    int w = rem - h * WW;
    float gx = -1.0f + (float)w * (2.0f / (float)(WW - 1));
    float gy = -1.0f + (float)h * (2.0f / (float)(HH - 1));

    const float4* sp = (const float4*)ws + (size_t)b * NS * 2;

    float r = 0.0f, g = 0.0f, bl = 0.0f;
#pragma unroll 3
    for (int j = 0; j < NS; ++j) {
        float4 a = sp[2 * j + 0];     // px, py, negc, cr  (wave-uniform load)
        float4 c = sp[2 * j + 1];     // cg, cb, -, -
        float dx = gx - a.x;
        float dy = gy - a.y;
        float d2 = fmaf(dy, dy, dx * dx);
        float wgt = __builtin_amdgcn_exp2f(d2 * a.z);  // a.z < 0
        r  = fmaf(wgt, a.w, r);
        g  = fmaf(wgt, c.x, g);
        bl = fmaf(wgt, c.y, bl);
    }
    // weights >= 0 and colors >= 0, so only the upper clip matters
    float* o = out + (size_t)p * 3;
    o[0] = fminf(r, 1.0f);
    o[1] = fminf(g, 1.0f);
    o[2] = fminf(bl, 1.0f);
}

// Fallback if ws is too small: read raw inputs directly (uniform index).
__global__ __launch_bounds__(256) void splat_render_direct(const float* __restrict__ pos,
                                                           const float* __restrict__ col,
                                                           const float* __restrict__ siz,
                                                           float* __restrict__ out) {
    int p = blockIdx.x * 256 + threadIdx.x;
    int b   = p / (HH * WW);
    int rem = p - b * (HH * WW);
    int h = rem / WW;
    int w = rem - h * WW;
    float gx = -1.0f + (float)w * (2.0f / (float)(WW - 1));
    float gy = -1.0f + (float)h * (2.0f / (float)(HH - 1));

    const float* pb = pos + (size_t)b * NS * 2;
    const float* cb = col + (size_t)b * NS * 3;
    const float* sb = siz + (size_t)b * NS;

    float r = 0.0f, g = 0.0f, bl = 0.0f;
    for (int j = 0; j < NS; ++j) {
        float px = pb[2 * j], py = pb[2 * j + 1];
        float s  = sb[j] * (2.0f / (float)HH);
        float itv = 1.0f / (2.0f * s * s + 1e-8f);
        float negc = -itv * 1.44269504088896340736f;
        float dx = gx - px;
        float dy = gy - py;
        float d2 = fmaf(dy, dy, dx * dx);
        float wgt = __builtin_amdgcn_exp2f(d2 * negc);
        r  = fmaf(wgt, cb[3 * j + 0], r);
        g  = fmaf(wgt, cb[3 * j + 1], g);
        bl = fmaf(wgt, cb[3 * j + 2], bl);
    }
    float* o = out + (size_t)p * 3;
    o[0] = fminf(r, 1.0f);
    o[1] = fminf(g, 1.0f);
    o[2] = fminf(bl, 1.0f);
}

extern "C" void kernel_launch(void* const* d_in, const int* in_sizes, int n_in,
                              void* d_out, int out_size, void* d_ws, size_t ws_size,
                              hipStream_t stream) {
    const float* pos = (const float*)d_in[0];
    const float* col = (const float*)d_in[1];
    const float* siz = (const float*)d_in[2];
    float* out = (float*)d_out;

    const size_t ws_needed = (size_t)BB * NS * 8 * sizeof(float);
    if (ws_size >= ws_needed) {
        float* ws = (float*)d_ws;
        splat_prep<<<(BB * NS + 255) / 256, 256, 0, stream>>>(pos, col, siz, ws);
        splat_render<<<NPIX / 256, 256, 0, stream>>>(ws, out);
    } else {
        splat_render_direct<<<NPIX / 256, 256, 0, stream>>>(pos, col, siz, out);
    }
}

// Round 2
// 101.727 us; speedup vs baseline: 3.6051x; 3.6051x over previous
//
#include <hip/hip_runtime.h>
#include <math.h>

#define HH 224
#define WW 224
#define NS 381                   // splats per image
#define BB 16                    // batch
#define NPIX (BB * HH * WW)      // 802816
#define PPT 4                    // pixels per thread (consecutive in x)
#define TPB 256
#define PIX_PER_BLK (PPT * TPB)  // 1024
#define BLKS_PER_IMG ((HH * WW) / PIX_PER_BLK)  // 49 (exact)
#define NBLK (BB * BLKS_PER_IMG)                // 784
#define NS_PAD 384               // pad with dummy splats for clean unroll
#define CUTOFF -19.93f           // exp2 arg cutoff -> weight < 1e-6

// Pack per-splat constants, prescaled so weight = exp2(-((gx*s - px*s)^2 + (gy*s - py*s)^2)):
//   s = sqrt(inv_two_var * log2(e));  A = {s, -px*s, -py*s, cr};  C = {cg, cb, 0, 0}
__global__ __launch_bounds__(256) void splat_prep(const float* __restrict__ pos,
                                                  const float* __restrict__ col,
                                                  const float* __restrict__ siz,
                                                  float4* __restrict__ ws) {
    int i = blockIdx.x * 256 + threadIdx.x;
    if (i >= BB * NS) return;
    float px = pos[2 * i + 0];
    float py = pos[2 * i + 1];
    float cr = col[3 * i + 0];
    float cg = col[3 * i + 1];
    float cb = col[3 * i + 2];
    float sg = siz[i] * (2.0f / (float)HH);
    float itv = 1.0f / (2.0f * sg * sg + 1e-8f);
    float ss = sqrtf(itv * 1.44269504088896340736f);
    ws[2 * i + 0] = make_float4(ss, -px * ss, -py * ss, cr);
    ws[2 * i + 1] = make_float4(cg, cb, 0.0f, 0.0f);
}

__global__ __launch_bounds__(TPB) void splat_render(const float4* __restrict__ ws,
                                                    float* __restrict__ out) {
    __shared__ float4 lds[NS_PAD * 2];

    int blk = blockIdx.x;
    int b = blk / BLKS_PER_IMG;                 // uniform per block (scalar)
    int blk_in_img = blk - b * BLKS_PER_IMG;

    // Stage this image's splats into LDS (coalesced), plus dummy tail splats
    // whose -dy^2 = -1e6 always fails the cutoff test.
    const float4* src = ws + (size_t)b * NS * 2;
    for (int i = threadIdx.x; i < NS * 2; i += TPB) lds[i] = src[i];
    if (threadIdx.x < (NS_PAD - NS) * 2)
        lds[NS * 2 + threadIdx.x] = make_float4(0.0f, 0.0f, 1000.0f, 0.0f);
    __syncthreads();

    int p0 = blk_in_img * PIX_PER_BLK + threadIdx.x * PPT;  // pixel index in image
    int h = p0 / WW;
    int w0 = p0 - h * WW;
    const float gstep = 2.0f / (float)(WW - 1);
    float gy  = -1.0f + (float)h * (2.0f / (float)(HH - 1));
    float gx0 = -1.0f + (float)w0 * gstep;
    float gx1 = gx0 + gstep;
    float gx2 = gx0 + 2.0f * gstep;
    float gx3 = gx0 + 3.0f * gstep;

    float r0 = 0.f, g0 = 0.f, b0 = 0.f;
    float r1 = 0.f, g1 = 0.f, b1 = 0.f;
    float r2 = 0.f, g2 = 0.f, b2 = 0.f;
    float r3 = 0.f, g3 = 0.f, b3 = 0.f;

#pragma unroll 4
    for (int j = 0; j < NS_PAD; ++j) {
        float4 A = lds[2 * j + 0];   // {s, -px*s, -py*s, cr} broadcast read
        float4 C = lds[2 * j + 1];   // {cg, cb, -, -}
        float dy  = fmaf(gy, A.x, A.z);
        float ndd = -(dy * dy);      // -(dy')^2; weight <= exp2(ndd)
        if (ndd > CUTOFF) {
            float dx0 = fmaf(gx0, A.x, A.y);
            float dx1 = fmaf(gx1, A.x, A.y);
            float dx2 = fmaf(gx2, A.x, A.y);
            float dx3 = fmaf(gx3, A.x, A.y);
            float we0 = __builtin_amdgcn_exp2f(fmaf(-dx0, dx0, ndd));
            float we1 = __builtin_amdgcn_exp2f(fmaf(-dx1, dx1, ndd));
            float we2 = __builtin_amdgcn_exp2f(fmaf(-dx2, dx2, ndd));
            float we3 = __builtin_amdgcn_exp2f(fmaf(-dx3, dx3, ndd));
            r0 = fmaf(we0, A.w, r0); g0 = fmaf(we0, C.x, g0); b0 = fmaf(we0, C.y, b0);
            r1 = fmaf(we1, A.w, r1); g1 = fmaf(we1, C.x, g1); b1 = fmaf(we1, C.y, b1);
            r2 = fmaf(we2, A.w, r2); g2 = fmaf(we2, C.x, g2); b2 = fmaf(we2, C.y, b2);
            r3 = fmaf(we3, A.w, r3); g3 = fmaf(we3, C.x, g3); b3 = fmaf(we3, C.y, b3);
        }
    }

    // 12 consecutive floats per thread -> 3 coalesced float4 stores (48B, 16B-aligned)
    float4* o4 = (float4*)(out + ((size_t)b * (HH * WW) + p0) * 3);
    o4[0] = make_float4(fminf(r0, 1.f), fminf(g0, 1.f), fminf(b0, 1.f), fminf(r1, 1.f));
    o4[1] = make_float4(fminf(g1, 1.f), fminf(b1, 1.f), fminf(r2, 1.f), fminf(g2, 1.f));
    o4[2] = make_float4(fminf(b2, 1.f), fminf(r3, 1.f), fminf(g3, 1.f), fminf(b3, 1.f));
}

// Fallback if ws is too small: read raw inputs directly (uniform index).
__global__ __launch_bounds__(256) void splat_render_direct(const float* __restrict__ pos,
                                                           const float* __restrict__ col,
                                                           const float* __restrict__ siz,
                                                           float* __restrict__ out) {
    int p = blockIdx.x * 256 + threadIdx.x;
    int b   = p / (HH * WW);
    int rem = p - b * (HH * WW);
    int h = rem / WW;
    int w = rem - h * WW;
    float gx = -1.0f + (float)w * (2.0f / (float)(WW - 1));
    float gy = -1.0f + (float)h * (2.0f / (float)(HH - 1));

    const float* pb = pos + (size_t)b * NS * 2;
    const float* cb = col + (size_t)b * NS * 3;
    const float* sb = siz + (size_t)b * NS;

    float r = 0.0f, g = 0.0f, bl = 0.0f;
    for (int j = 0; j < NS; ++j) {
        float px = pb[2 * j], py = pb[2 * j + 1];
        float s  = sb[j] * (2.0f / (float)HH);
        float itv = 1.0f / (2.0f * s * s + 1e-8f);
        float negc = -itv * 1.44269504088896340736f;
        float dx = gx - px;
        float dy = gy - py;
        float d2 = fmaf(dy, dy, dx * dx);
        float wgt = __builtin_amdgcn_exp2f(d2 * negc);
        r  = fmaf(wgt, cb[3 * j + 0], r);
        g  = fmaf(wgt, cb[3 * j + 1], g);
        bl = fmaf(wgt, cb[3 * j + 2], bl);
    }
    float* o = out + (size_t)p * 3;
    o[0] = fminf(r, 1.0f);
    o[1] = fminf(g, 1.0f);
    o[2] = fminf(bl, 1.0f);
}

extern "C" void kernel_launch(void* const* d_in, const int* in_sizes, int n_in,
                              void* d_out, int out_size, void* d_ws, size_t ws_size,
                              hipStream_t stream) {
    const float* pos = (const float*)d_in[0];
    const float* col = (const float*)d_in[1];
    const float* siz = (const float*)d_in[2];
    float* out = (float*)d_out;

    const size_t ws_needed = (size_t)BB * NS * 2 * sizeof(float4);
    if (ws_size >= ws_needed) {
        float4* ws = (float4*)d_ws;
        splat_prep<<<(BB * NS + 255) / 256, 256, 0, stream>>>(pos, col, siz, ws);
        splat_render<<<NBLK, TPB, 0, stream>>>(ws, out);
    } else {
        splat_render_direct<<<NPIX / 256, 256, 0, stream>>>(pos, col, siz, out);
    }
}

// Round 3
// 77.577 us; speedup vs baseline: 4.7274x; 1.3113x over previous
//
#include <hip/hip_runtime.h>
#include <math.h>

#define HH 224
#define WW 224
#define NS 381                   // splats per image
#define BB 16                    // batch
#define NPIX (BB * HH * WW)      // 802816
#define TPB 256
#define TILE_W 32
#define TILE_H 32
#define TILES_X (WW / TILE_W)    // 7
#define BLKS_PER_IMG (TILES_X * (HH / TILE_H))  // 49
#define NBLK (BB * BLKS_PER_IMG)                // 784
#define NS_PAD 384
#define CUT 19.93f               // exp2 cutoff: weight < 2^-19.93 ~ 1e-6

// Pack per-splat constants, prescaled so weight = exp2(-((gx*ss + pxs)^2 + (gy*ss + pys)^2)):
//   ss = sqrt(inv_two_var * log2(e));  A = {ss, -px*ss, -py*ss, cr};  C = {cg, cb, 0, 0}
__global__ __launch_bounds__(256) void splat_prep(const float* __restrict__ pos,
                                                  const float* __restrict__ col,
                                                  const float* __restrict__ siz,
                                                  float4* __restrict__ ws) {
    int i = blockIdx.x * 256 + threadIdx.x;
    if (i >= BB * NS) return;
    float px = pos[2 * i + 0];
    float py = pos[2 * i + 1];
    float cr = col[3 * i + 0];
    float cg = col[3 * i + 1];
    float cb = col[3 * i + 2];
    float sg = siz[i] * (2.0f / (float)HH);
    float itv = 1.0f / (2.0f * sg * sg + 1e-8f);
    float ss = sqrtf(itv * 1.44269504088896340736f);
    ws[2 * i + 0] = make_float4(ss, -px * ss, -py * ss, cr);
    ws[2 * i + 1] = make_float4(cg, cb, 0.0f, 0.0f);
}

__global__ __launch_bounds__(TPB) void splat_render(const float4* __restrict__ ws,
                                                    float* __restrict__ out) {
    __shared__ float4 geo[NS_PAD];
    __shared__ float4 colr[NS_PAD];
    __shared__ int cnt;

    int blk = blockIdx.x;
    int b = blk / BLKS_PER_IMG;
    int t = blk - b * BLKS_PER_IMG;
    int tile_y = t / TILES_X;
    int tile_x = t - tile_y * TILES_X;

    if (threadIdx.x == 0) cnt = 0;
    __syncthreads();

    const float gstep = 2.0f / (float)(WW - 1);
    float x0 = -1.0f + (float)(tile_x * TILE_W) * gstep;
    float x1 = x0 + (float)(TILE_W - 1) * gstep;
    float y0 = -1.0f + (float)(tile_y * TILE_H) * gstep;
    float y1 = y0 + (float)(TILE_H - 1) * gstep;

    const float4* src = ws + (size_t)b * NS * 2;
    int lane = threadIdx.x & 63;

    // ---- cull + compact into LDS ----
    for (int r = 0; r < 2; ++r) {
        int i = threadIdx.x + r * TPB;
        bool pass = false;
        float4 A = make_float4(0.f, 0.f, 0.f, 0.f);
        float4 C = make_float4(0.f, 0.f, 0.f, 0.f);
        if (i < NS) {
            A = src[2 * i + 0];
            C = src[2 * i + 1];
            float ss = A.x;
            float u = -A.y;                 // px*ss
            float v = -A.z;                 // py*ss
            float dx = fmaxf(fmaxf(x0 * ss - u, u - x1 * ss), 0.0f);
            float dy = fmaxf(fmaxf(y0 * ss - v, v - y1 * ss), 0.0f);
            pass = fmaf(dx, dx, dy * dy) < CUT;   // min dist^2 (scaled) to tile rect
        }
        unsigned long long mask = __ballot(pass);
        int pos = __popcll(mask & ((1ull << lane) - 1ull));
        int tot = __popcll(mask);
        int base = 0;
        if (lane == 0 && tot) base = atomicAdd(&cnt, tot);
        base = __shfl(base, 0);
        if (pass) {
            geo[base + pos]  = A;
            colr[base + pos] = C;
        }
    }
    __syncthreads();
    int m = cnt;
    int m4 = (m + 3) & ~3;      // pad to multiple of 4 with always-fail dummies
    if (threadIdx.x < (m4 - m)) {
        geo[m + threadIdx.x]  = make_float4(0.f, 0.f, 1000.0f, 0.f);
        colr[m + threadIdx.x] = make_float4(0.f, 0.f, 0.f, 0.f);
    }
    __syncthreads();
    m4 = __builtin_amdgcn_readfirstlane(m4);

    // ---- render 4 pixels/thread over survivors ----
    int tx = threadIdx.x & 7;           // 8 x-groups of 4 px = 32 px
    int ty = threadIdx.x >> 3;          // 32 rows
    int w0 = tile_x * TILE_W + tx * 4;
    int h  = tile_y * TILE_H + ty;
    float gy  = -1.0f + (float)h * gstep;
    float gx0 = -1.0f + (float)w0 * gstep;
    float gx1 = gx0 + gstep;
    float gx2 = gx0 + 2.0f * gstep;
    float gx3 = gx0 + 3.0f * gstep;

    float r0 = 0.f, g0 = 0.f, b0 = 0.f;
    float r1 = 0.f, g1 = 0.f, b1 = 0.f;
    float r2 = 0.f, g2 = 0.f, b2 = 0.f;
    float r3 = 0.f, g3 = 0.f, b3 = 0.f;

#pragma unroll 4
    for (int j = 0; j < m4; ++j) {
        float4 A = geo[j];              // {ss, -px*ss, -py*ss, cr} broadcast
        float4 C = colr[j];             // {cg, cb, -, -}
        float dy  = fmaf(gy, A.x, A.z);
        float ndd = -(dy * dy);         // weight <= exp2(ndd)
        if (ndd > -CUT) {
            float dx0 = fmaf(gx0, A.x, A.y);
            float dx1 = fmaf(gx1, A.x, A.y);
            float dx2 = fmaf(gx2, A.x, A.y);
            float dx3 = fmaf(gx3, A.x, A.y);
            float we0 = __builtin_amdgcn_exp2f(fmaf(-dx0, dx0, ndd));
            float we1 = __builtin_amdgcn_exp2f(fmaf(-dx1, dx1, ndd));
            float we2 = __builtin_amdgcn_exp2f(fmaf(-dx2, dx2, ndd));
            float we3 = __builtin_amdgcn_exp2f(fmaf(-dx3, dx3, ndd));
            r0 = fmaf(we0, A.w, r0); g0 = fmaf(we0, C.x, g0); b0 = fmaf(we0, C.y, b0);
            r1 = fmaf(we1, A.w, r1); g1 = fmaf(we1, C.x, g1); b1 = fmaf(we1, C.y, b1);
            r2 = fmaf(we2, A.w, r2); g2 = fmaf(we2, C.x, g2); b2 = fmaf(we2, C.y, b2);
            r3 = fmaf(we3, A.w, r3); g3 = fmaf(we3, C.x, g3); b3 = fmaf(we3, C.y, b3);
        }
    }

    float4* o4 = (float4*)(out + ((size_t)b * (HH * WW) + (size_t)h * WW + w0) * 3);
    o4[0] = make_float4(fminf(r0, 1.f), fminf(g0, 1.f), fminf(b0, 1.f), fminf(r1, 1.f));
    o4[1] = make_float4(fminf(g1, 1.f), fminf(b1, 1.f), fminf(r2, 1.f), fminf(g2, 1.f));
    o4[2] = make_float4(fminf(b2, 1.f), fminf(r3, 1.f), fminf(g3, 1.f), fminf(b3, 1.f));
}

// Fallback if ws is too small: read raw inputs directly (uniform index).
__global__ __launch_bounds__(256) void splat_render_direct(const float* __restrict__ pos,
                                                           const float* __restrict__ col,
                                                           const float* __restrict__ siz,
                                                           float* __restrict__ out) {
    int p = blockIdx.x * 256 + threadIdx.x;
    int b   = p / (HH * WW);
    int rem = p - b * (HH * WW);
    int h = rem / WW;
    int w = rem - h * WW;
    float gx = -1.0f + (float)w * (2.0f / (float)(WW - 1));
    float gy = -1.0f + (float)h * (2.0f / (float)(HH - 1));

    const float* pb = pos + (size_t)b * NS * 2;
    const float* cb = col + (size_t)b * NS * 3;
    const float* sb = siz + (size_t)b * NS;

    float r = 0.0f, g = 0.0f, bl = 0.0f;
    for (int j = 0; j < NS; ++j) {
        float px = pb[2 * j], py = pb[2 * j + 1];
        float s  = sb[j] * (2.0f / (float)HH);
        float itv = 1.0f / (2.0f * s * s + 1e-8f);
        float negc = -itv * 1.44269504088896340736f;
        float dx = gx - px;
        float dy = gy - py;
        float d2 = fmaf(dy, dy, dx * dx);
        float wgt = __builtin_amdgcn_exp2f(d2 * negc);
        r  = fmaf(wgt, cb[3 * j + 0], r);
        g  = fmaf(wgt, cb[3 * j + 1], g);
        bl = fmaf(wgt, cb[3 * j + 2], bl);
    }
    float* o = out + (size_t)p * 3;
    o[0] = fminf(r, 1.0f);
    o[1] = fminf(g, 1.0f);
    o[2] = fminf(bl, 1.0f);
}

extern "C" void kernel_launch(void* const* d_in, const int* in_sizes, int n_in,
                              void* d_out, int out_size, void* d_ws, size_t ws_size,
                              hipStream_t stream) {
    const float* pos = (const float*)d_in[0];
    const float* col = (const float*)d_in[1];
    const float* siz = (const float*)d_in[2];
    float* out = (float*)d_out;

    const size_t ws_needed = (size_t)BB * NS * 2 * sizeof(float4);
    if (ws_size >= ws_needed) {
        float4* ws = (float4*)d_ws;
        splat_prep<<<(BB * NS + 255) / 256, 256, 0, stream>>>(pos, col, siz, ws);
        splat_render<<<NBLK, TPB, 0, stream>>>(ws, out);
    } else {
        splat_render_direct<<<NPIX / 256, 256, 0, stream>>>(pos, col, siz, out);
    }
}